// Round 6
// baseline (92.593 us; speedup 1.0000x reference)
//
#include <hip/hip_runtime.h>
#include <hip/hip_bf16.h>

#define SCALING 0.17677669529663687f   // HD^-0.5

typedef __attribute__((ext_vector_type(8))) short bf8;      // 8 bf16
typedef __attribute__((ext_vector_type(4))) short bf4;      // 4 bf16
typedef _Float16 half8 __attribute__((ext_vector_type(8))); // 8 f16
typedef _Float16 half4 __attribute__((ext_vector_type(4))); // 4 f16
typedef __attribute__((ext_vector_type(4))) float floatx4;  // MFMA C/D

__device__ __forceinline__ short f2bf(float f) {
    union { float f; unsigned u; } v; v.f = f;
    unsigned u = v.u;
    return (short)((u + 0x7FFFu + ((u >> 16) & 1u)) >> 16);  // RTNE
}
// packed pair convert -> v_cvt_pk_bf16_f32
__device__ __forceinline__ void f2bf_pk(float x, float y, short* d) {
    union { __hip_bfloat162 h; short s[2]; } u;
    u.h = __float22bfloat162_rn(make_float2(x, y));
    d[0] = u.s[0]; d[1] = u.s[1];
}
__device__ __forceinline__ bf4 f2bf4(float4 x) {
    bf4 r;
    short t[2];
    f2bf_pk(x.x, x.y, t); r[0] = t[0]; r[1] = t[1];
    f2bf_pk(x.z, x.w, t); r[2] = t[0]; r[3] = t[1];
    return r;
}

#define PSTR 264   // Pl row stride (shorts): 132 dwords == 4 mod 32
#define VSTR 72    // Vt/Ps row stride (halfs): 36 dwords == 4 mod 32

// ---------------------------------------------------------------------------
// ONE fused kernel.  Block = (n-tile of 32, batch).  512 threads, 1 block/CU.
// Phase 1: MFMA-project rows [Q(32,pre-scaled) | K(64: j=n0-32..n0+31) |
//          V(64)] x 256 cols.  Q,K -> Pl (bf16); V -> Vt TRANSPOSED (f16).
//          Software-pipelined k-loop: step i+1 loads overlap step i MFMAs.
// Phase 2: one head per wave; banded QK^T (6 MFMA), shfl softmax, PV (8 f16
//          MFMA via Ps relayout scratch), direct stores.
// ---------------------------------------------------------------------------
__global__ __launch_bounds__(512, 2) void fused_kernel(
    const float* __restrict__ q, const float* __restrict__ k,
    const float* __restrict__ v, const float* __restrict__ W,
    const float* __restrict__ bias, float* __restrict__ out)
{
    __shared__ short    Pl[96][PSTR];     // 50688 B  projected Q|K (bf16)
    __shared__ _Float16 Vt[256][VSTR];    // 36864 B  projected V, [d][i] (f16)
    __shared__ _Float16 Ps[8][32][VSTR];  // 36864 B  per-wave P scratch (f16)
    __shared__ short    As[160][40];      // 12800 B  X staging
    __shared__ short    Bs[256][40];      // 20480 B  W staging

    const int tid = threadIdx.x;
    const int n0  = blockIdx.x * 32;
    const int b   = blockIdx.y;
    const int lane = tid & 63, wid = tid >> 6;
    const int wm = wid & 1, wn = wid >> 1;       // 2m x 4n wave grid
    const int quad = lane >> 4, l16 = lane & 15;

    // ---- Phase 1 staging coords ----
    int a_row[3]; int a_c4[3]; const float* a_ptr[3];
    #pragma unroll
    for (int i = 0; i < 3; i++) {
        int idx = tid + i * 512;
        if (idx < 1280) {
            int r = idx >> 3;
            a_row[i] = r;
            a_c4[i]  = (idx & 7) * 4;
            const float* p;
            if (r < 32) {
                p = q + (size_t)(b * 4096 + n0 + r) * 256;
            } else if (r < 96) {
                int j = n0 + r - 64;
                p = (j >= 0) ? (k + (size_t)(b * 4096 + j) * 256) : nullptr;
            } else {
                int j = n0 + r - 128;
                p = (j >= 0) ? (v + (size_t)(b * 4096 + j) * 256) : nullptr;
            }
            a_ptr[i] = p;
        } else { a_row[i] = -1; a_c4[i] = 0; a_ptr[i] = nullptr; }
    }
    int w_row[4], w_c4[4];
    #pragma unroll
    for (int i = 0; i < 4; i++) {
        int idx = tid + i * 512;
        w_row[i] = idx >> 3;
        w_c4[i]  = (idx & 7) * 4;
    }

    floatx4 acc[5][4];
    #pragma unroll
    for (int mt = 0; mt < 5; mt++)
        #pragma unroll
        for (int nt = 0; nt < 4; nt++) acc[mt][nt] = (floatx4)0.0f;

    // prologue loads (k0 = 0)
    float4 xa[3], wv[4];
    #pragma unroll
    for (int i = 0; i < 3; i++)
        xa[i] = a_ptr[i] ? *(const float4*)(a_ptr[i] + a_c4[i])
                         : make_float4(0.f, 0.f, 0.f, 0.f);
    #pragma unroll
    for (int i = 0; i < 4; i++)
        wv[i] = *(const float4*)(W + (size_t)w_row[i] * 256 + w_c4[i]);

    #pragma unroll
    for (int step = 0; step < 8; step++) {
        const int k0n = (step + 1) * 32;
        bf4 ab[3], wb[4];
        #pragma unroll
        for (int i = 0; i < 3; i++) ab[i] = f2bf4(xa[i]);
        #pragma unroll
        for (int i = 0; i < 4; i++) wb[i] = f2bf4(wv[i]);
        __syncthreads();   // prior iter frag reads done
        #pragma unroll
        for (int i = 0; i < 3; i++)
            if (a_row[i] >= 0) *(bf4*)&As[a_row[i]][a_c4[i]] = ab[i];
        #pragma unroll
        for (int i = 0; i < 4; i++)
            *(bf4*)&Bs[w_row[i]][w_c4[i]] = wb[i];
        __syncthreads();

        // prefetch next step's globals (overlaps frag reads + MFMAs)
        if (step < 7) {
            #pragma unroll
            for (int i = 0; i < 3; i++)
                xa[i] = a_ptr[i] ? *(const float4*)(a_ptr[i] + k0n + a_c4[i])
                                 : make_float4(0.f, 0.f, 0.f, 0.f);
            #pragma unroll
            for (int i = 0; i < 4; i++)
                wv[i] = *(const float4*)(W + (size_t)w_row[i] * 256 + k0n + w_c4[i]);
        }

        bf8 af[5], bfr[4];
        #pragma unroll
        for (int mt = 0; mt < 5; mt++)
            af[mt] = *(const bf8*)&As[wm * 80 + mt * 16 + l16][quad * 8];
        #pragma unroll
        for (int nt = 0; nt < 4; nt++)
            bfr[nt] = *(const bf8*)&Bs[wn * 64 + nt * 16 + l16][quad * 8];
        #pragma unroll
        for (int mt = 0; mt < 5; mt++)
            #pragma unroll
            for (int nt = 0; nt < 4; nt++)
                acc[mt][nt] = __builtin_amdgcn_mfma_f32_16x16x32_bf16(
                    af[mt], bfr[nt], acc[mt][nt], 0, 0, 0);
    }

    // Epilogue: +bias; Q rows pre-scaled by SCALING -> Pl; K -> Pl; V -> Vt^T
    #pragma unroll
    for (int nt = 0; nt < 4; nt++) {
        int col = wn * 64 + nt * 16 + l16;
        float bv = bias[col];
        #pragma unroll
        for (int mt = 0; mt < 5; mt++) {
            int rb = wm * 80 + mt * 16 + quad * 4;   // wave-uniform band per (wm,mt)
            if (rb < 96) {
                const bool isQ = (rb < 32);
                #pragma unroll
                for (int r = 0; r < 4; r++) {
                    float val = acc[mt][nt][r] + bv;
                    Pl[rb + r][col] = f2bf(isQ ? val * SCALING : val);
                }
            } else {
                half4 hv;
                #pragma unroll
                for (int r = 0; r < 4; r++) hv[r] = (_Float16)(acc[mt][nt][r] + bv);
                *(half4*)&Vt[col][rb - 96] = hv;
            }
        }
    }
    __syncthreads();

    // ---- Phase 2: one head per wave ----
    const int h  = wid;
    const int cb = h * 32;

    bf8 qf[2], kf[4];
    #pragma unroll
    for (int mt = 0; mt < 2; mt++)
        qf[mt] = *(const bf8*)&Pl[mt * 16 + l16][cb + quad * 8];
    #pragma unroll
    for (int jt = 0; jt < 4; jt++)
        kf[jt] = *(const bf8*)&Pl[32 + jt * 16 + l16][cb + quad * 8];

    floatx4 S[2][4];
    S[0][0] = __builtin_amdgcn_mfma_f32_16x16x32_bf16(qf[0], kf[0], (floatx4)0.f, 0, 0, 0);
    S[0][1] = __builtin_amdgcn_mfma_f32_16x16x32_bf16(qf[0], kf[1], (floatx4)0.f, 0, 0, 0);
    S[0][2] = __builtin_amdgcn_mfma_f32_16x16x32_bf16(qf[0], kf[2], (floatx4)0.f, 0, 0, 0);
    S[1][1] = __builtin_amdgcn_mfma_f32_16x16x32_bf16(qf[1], kf[1], (floatx4)0.f, 0, 0, 0);
    S[1][2] = __builtin_amdgcn_mfma_f32_16x16x32_bf16(qf[1], kf[2], (floatx4)0.f, 0, 0, 0);
    S[1][3] = __builtin_amdgcn_mfma_f32_16x16x32_bf16(qf[1], kf[3], (floatx4)0.f, 0, 0, 0);

    // Band mask + softmax (valid iff n+1 <= i <= n+32), shfl over l16 group
    float p[2][3][4], inv[2][4];
    #pragma unroll
    for (int mt = 0; mt < 2; mt++) {
        #pragma unroll
        for (int r = 0; r < 4; r++) {
            int n = mt * 16 + quad * 4 + r;
            float sv[3], mx = -3.0e38f;
            #pragma unroll
            for (int u = 0; u < 3; u++) {
                int i = (u + mt) * 16 + l16;
                bool valid = (i > n) && (i <= n + 32);
                sv[u] = valid ? S[mt][u + mt][r] : -3.0e38f;
                mx = fmaxf(mx, sv[u]);
            }
            #pragma unroll
            for (int off = 1; off < 16; off <<= 1)
                mx = fmaxf(mx, __shfl_xor(mx, off, 64));
            float lsum = 0.f;
            #pragma unroll
            for (int u = 0; u < 3; u++) {
                float pv = (sv[u] > -1.0e38f) ? __expf(sv[u] - mx) : 0.f;
                p[mt][u][r] = pv;
                lsum += pv;
            }
            #pragma unroll
            for (int off = 1; off < 16; off <<= 1)
                lsum += __shfl_xor(lsum, off, 64);
            inv[mt][r] = 1.0f / lsum;
        }
    }

    // P -> per-wave scratch (f16, C->A relayout); zero out-of-band tiles
    _Float16 (*myPs)[VSTR] = Ps[h];
    #pragma unroll
    for (int mt = 0; mt < 2; mt++) {
        int zjt = (mt == 0) ? 3 : 0;
        #pragma unroll
        for (int r = 0; r < 4; r++) {
            int row = mt * 16 + quad * 4 + r;
            #pragma unroll
            for (int u = 0; u < 3; u++)
                myPs[row][(u + mt) * 16 + l16] = (_Float16)p[mt][u][r];
            myPs[row][zjt * 16 + l16] = (_Float16)0.f;
        }
    }

    half8 pf[2][2], vf[2][2];
    #pragma unroll
    for (int mt = 0; mt < 2; mt++)
        #pragma unroll
        for (int ks = 0; ks < 2; ks++)
            pf[mt][ks] = *(const half8*)&myPs[mt * 16 + l16][ks * 32 + quad * 8];
    #pragma unroll
    for (int dt = 0; dt < 2; dt++)
        #pragma unroll
        for (int ks = 0; ks < 2; ks++)
            vf[dt][ks] = *(const half8*)&Vt[cb + dt * 16 + l16][ks * 32 + quad * 8];

    floatx4 O[2][2];
    #pragma unroll
    for (int mt = 0; mt < 2; mt++)
        #pragma unroll
        for (int dt = 0; dt < 2; dt++) {
            O[mt][dt] = (floatx4)0.f;
            #pragma unroll
            for (int ks = 0; ks < 2; ks++)
                O[mt][dt] = __builtin_amdgcn_mfma_f32_16x16x32_f16(
                    pf[mt][ks], vf[dt][ks], O[mt][dt], 0, 0, 0);
        }

    const size_t obase = ((size_t)b * 4096 + n0) * 256;
    #pragma unroll
    for (int mt = 0; mt < 2; mt++)
        #pragma unroll
        for (int dt = 0; dt < 2; dt++)
            #pragma unroll
            for (int r = 0; r < 4; r++) {
                int n = mt * 16 + quad * 4 + r;
                out[obase + (size_t)n * 256 + cb + dt * 16 + l16] =
                    O[mt][dt][r] * inv[mt][r];
            }
}

extern "C" void kernel_launch(void* const* d_in, const int* in_sizes, int n_in,
                              void* d_out, int out_size, void* d_ws, size_t ws_size,
                              hipStream_t stream) {
    (void)in_sizes; (void)n_in; (void)out_size; (void)d_ws; (void)ws_size;
    const float* q    = (const float*)d_in[0];
    const float* k    = (const float*)d_in[1];
    const float* v    = (const float*)d_in[2];
    const float* W    = (const float*)d_in[3];
    const float* bias = (const float*)d_in[4];
    float* outp = (float*)d_out;

    hipLaunchKernelGGL(fused_kernel, dim3(128, 2), dim3(512), 0, stream,
                       q, k, v, W, bias, outp);
}

// Round 7
// 92.259 us; speedup vs baseline: 1.0036x; 1.0036x over previous
//
#include <hip/hip_runtime.h>

#define SCALING 0.17677669529663687f   // HD^-0.5

typedef __attribute__((ext_vector_type(8))) short bf8;      // 8 bf16
typedef __attribute__((ext_vector_type(4))) short bf4;      // 4 bf16
typedef _Float16 half8 __attribute__((ext_vector_type(8))); // 8 f16
typedef _Float16 half4 __attribute__((ext_vector_type(4))); // 4 f16
typedef __attribute__((ext_vector_type(4))) float floatx4;  // MFMA C/D

__device__ __forceinline__ short f2bf(float f) {
    union { float f; unsigned u; } v; v.f = f;
    unsigned u = v.u;
    return (short)((u + 0x7FFFu + ((u >> 16) & 1u)) >> 16);  // RTNE
}

#define PSTR 264   // Pl row stride (shorts): 132 dwords == 4 mod 32
#define VSTR 72    // Vt/Ps row stride (halfs): 36 dwords == 4 mod 32

// ---------------------------------------------------------------------------
// ONE fused kernel.  Block = (n-tile of 32, batch).  512 threads, 1 block/CU.
// Phase 1: MFMA-project rows [Q(32,pre-scaled) | K(64: j=n0-32..n0+31) |
//          V(64)] x 256 cols.  Q,K -> Pl (bf16); V -> Vt TRANSPOSED (f16).
//          j<0 rows use zero input -> projection == bias (matches ref pad).
// Phase 2: one head per wave.  S = Q.K^T (6 MFMAs, banded), softmax in
//          C-layout regs (shfl_xor over 16-lane col group), P -> per-wave
//          Ps scratch (f16, C->A relayout), O = P.V via 8 f16 MFMAs,
//          scale by 1/l on C-frags, direct global stores.
// ---------------------------------------------------------------------------
__global__ __launch_bounds__(512, 2) void fused_kernel(
    const float* __restrict__ q, const float* __restrict__ k,
    const float* __restrict__ v, const float* __restrict__ W,
    const float* __restrict__ bias, float* __restrict__ out)
{
    __shared__ short    Pl[96][PSTR];     // 50688 B  projected Q|K (bf16)
    __shared__ _Float16 Vt[256][VSTR];    // 36864 B  projected V, [d][i] (f16)
    __shared__ _Float16 Ps[8][32][VSTR];  // 36864 B  per-wave P scratch (f16)
    __shared__ short    As[160][40];      // 12800 B  X staging
    __shared__ short    Bs[256][40];      // 20480 B  W staging

    const int tid = threadIdx.x;
    const int n0  = blockIdx.x * 32;
    const int b   = blockIdx.y;
    const int lane = tid & 63, wid = tid >> 6;
    const int wm = wid & 1, wn = wid >> 1;       // 2m x 4n wave grid
    const int quad = lane >> 4, l16 = lane & 15;

    // ---- Phase 1 staging coords ----
    int a_row[3]; int a_c4[3]; const float* a_ptr[3];
    #pragma unroll
    for (int i = 0; i < 3; i++) {
        int idx = tid + i * 512;
        if (idx < 1280) {
            int r = idx >> 3;
            a_row[i] = r;
            a_c4[i]  = (idx & 7) * 4;
            const float* p;
            if (r < 32) {
                p = q + (size_t)(b * 4096 + n0 + r) * 256;
            } else if (r < 96) {
                int j = n0 + r - 64;
                p = (j >= 0) ? (k + (size_t)(b * 4096 + j) * 256) : nullptr;
            } else {
                int j = n0 + r - 128;
                p = (j >= 0) ? (v + (size_t)(b * 4096 + j) * 256) : nullptr;
            }
            a_ptr[i] = p;
        } else { a_row[i] = -1; a_c4[i] = 0; a_ptr[i] = nullptr; }
    }
    int w_row[4], w_c4[4];
    #pragma unroll
    for (int i = 0; i < 4; i++) {
        int idx = tid + i * 512;
        w_row[i] = idx >> 3;
        w_c4[i]  = (idx & 7) * 4;
    }

    floatx4 acc[5][4];
    #pragma unroll
    for (int mt = 0; mt < 5; mt++)
        #pragma unroll
        for (int nt = 0; nt < 4; nt++) acc[mt][nt] = (floatx4)0.0f;

    for (int k0 = 0; k0 < 256; k0 += 32) {
        bf4 ab[3];
        #pragma unroll
        for (int i = 0; i < 3; i++) {
            float4 xa = make_float4(0.f, 0.f, 0.f, 0.f);
            if (a_ptr[i]) xa = *(const float4*)(a_ptr[i] + k0 + a_c4[i]);
            ab[i][0] = f2bf(xa.x); ab[i][1] = f2bf(xa.y);
            ab[i][2] = f2bf(xa.z); ab[i][3] = f2bf(xa.w);
        }
        bf4 wb[4];
        #pragma unroll
        for (int i = 0; i < 4; i++) {
            float4 wv = *(const float4*)(W + (size_t)w_row[i] * 256 + k0 + w_c4[i]);
            wb[i][0] = f2bf(wv.x); wb[i][1] = f2bf(wv.y);
            wb[i][2] = f2bf(wv.z); wb[i][3] = f2bf(wv.w);
        }
        __syncthreads();
        #pragma unroll
        for (int i = 0; i < 3; i++)
            if (a_row[i] >= 0) *(bf4*)&As[a_row[i]][a_c4[i]] = ab[i];
        #pragma unroll
        for (int i = 0; i < 4; i++)
            *(bf4*)&Bs[w_row[i]][w_c4[i]] = wb[i];
        __syncthreads();

        bf8 af[5], bfr[4];
        #pragma unroll
        for (int mt = 0; mt < 5; mt++)
            af[mt] = *(const bf8*)&As[wm * 80 + mt * 16 + l16][quad * 8];
        #pragma unroll
        for (int nt = 0; nt < 4; nt++)
            bfr[nt] = *(const bf8*)&Bs[wn * 64 + nt * 16 + l16][quad * 8];
        #pragma unroll
        for (int mt = 0; mt < 5; mt++)
            #pragma unroll
            for (int nt = 0; nt < 4; nt++)
                acc[mt][nt] = __builtin_amdgcn_mfma_f32_16x16x32_bf16(
                    af[mt], bfr[nt], acc[mt][nt], 0, 0, 0);
    }

    // Epilogue: +bias; Q rows pre-scaled by SCALING -> Pl; K -> Pl; V -> Vt^T
    #pragma unroll
    for (int nt = 0; nt < 4; nt++) {
        int col = wn * 64 + nt * 16 + l16;
        float bv = bias[col];
        #pragma unroll
        for (int mt = 0; mt < 5; mt++) {
            int rb = wm * 80 + mt * 16 + quad * 4;   // wave-uniform band per (wm,mt)
            if (rb < 96) {
                const bool isQ = (rb < 32);
                #pragma unroll
                for (int r = 0; r < 4; r++) {
                    float val = acc[mt][nt][r] + bv;
                    Pl[rb + r][col] = f2bf(isQ ? val * SCALING : val);
                }
            } else {
                half4 hv;
                #pragma unroll
                for (int r = 0; r < 4; r++) hv[r] = (_Float16)(acc[mt][nt][r] + bv);
                *(half4*)&Vt[col][rb - 96] = hv;
            }
        }
    }
    __syncthreads();

    // ---- Phase 2: one head per wave ----
    const int h  = wid;
    const int cb = h * 32;

    // S = Q.K^T : A-frags from Q rows, B-frags from K rows (both contiguous-d)
    bf8 qf[2], kf[4];
    #pragma unroll
    for (int mt = 0; mt < 2; mt++)
        qf[mt] = *(const bf8*)&Pl[mt * 16 + l16][cb + quad * 8];
    #pragma unroll
    for (int jt = 0; jt < 4; jt++)
        kf[jt] = *(const bf8*)&Pl[32 + jt * 16 + l16][cb + quad * 8];

    floatx4 S[2][4];
    S[0][0] = __builtin_amdgcn_mfma_f32_16x16x32_bf16(qf[0], kf[0], (floatx4)0.f, 0, 0, 0);
    S[0][1] = __builtin_amdgcn_mfma_f32_16x16x32_bf16(qf[0], kf[1], (floatx4)0.f, 0, 0, 0);
    S[0][2] = __builtin_amdgcn_mfma_f32_16x16x32_bf16(qf[0], kf[2], (floatx4)0.f, 0, 0, 0);
    S[1][1] = __builtin_amdgcn_mfma_f32_16x16x32_bf16(qf[1], kf[1], (floatx4)0.f, 0, 0, 0);
    S[1][2] = __builtin_amdgcn_mfma_f32_16x16x32_bf16(qf[1], kf[2], (floatx4)0.f, 0, 0, 0);
    S[1][3] = __builtin_amdgcn_mfma_f32_16x16x32_bf16(qf[1], kf[3], (floatx4)0.f, 0, 0, 0);

    // Band mask + softmax.  Row n = mt*16+quad*4+r; col i = jt*16+l16;
    // valid iff n+1 <= i <= n+32.  Row stats via shfl_xor over l16 group.
    float p[2][3][4], inv[2][4];
    #pragma unroll
    for (int mt = 0; mt < 2; mt++) {
        #pragma unroll
        for (int r = 0; r < 4; r++) {
            int n = mt * 16 + quad * 4 + r;
            float sv[3], mx = -3.0e38f;
            #pragma unroll
            for (int u = 0; u < 3; u++) {
                int i = (u + mt) * 16 + l16;
                bool valid = (i > n) && (i <= n + 32);
                sv[u] = valid ? S[mt][u + mt][r] : -3.0e38f;
                mx = fmaxf(mx, sv[u]);
            }
            #pragma unroll
            for (int off = 1; off < 16; off <<= 1)
                mx = fmaxf(mx, __shfl_xor(mx, off, 64));
            float lsum = 0.f;
            #pragma unroll
            for (int u = 0; u < 3; u++) {
                float pv = (sv[u] > -1.0e38f) ? __expf(sv[u] - mx) : 0.f;
                p[mt][u][r] = pv;
                lsum += pv;
            }
            #pragma unroll
            for (int off = 1; off < 16; off <<= 1)
                lsum += __shfl_xor(lsum, off, 64);
            inv[mt][r] = 1.0f / lsum;
        }
    }

    // P -> per-wave scratch (f16), C-layout writes; zero out-of-band tiles
    _Float16 (*myPs)[VSTR] = Ps[h];
    #pragma unroll
    for (int mt = 0; mt < 2; mt++) {
        int zjt = (mt == 0) ? 3 : 0;
        #pragma unroll
        for (int r = 0; r < 4; r++) {
            int row = mt * 16 + quad * 4 + r;
            #pragma unroll
            for (int u = 0; u < 3; u++)
                myPs[row][(u + mt) * 16 + l16] = (_Float16)p[mt][u][r];
            myPs[row][zjt * 16 + l16] = (_Float16)0.f;
        }
    }
    // same-wave producer/consumer: compiler inserts lgkmcnt wait

    half8 pf[2][2], vf[2][2];
    #pragma unroll
    for (int mt = 0; mt < 2; mt++)
        #pragma unroll
        for (int ks = 0; ks < 2; ks++)
            pf[mt][ks] = *(const half8*)&myPs[mt * 16 + l16][ks * 32 + quad * 8];
    #pragma unroll
    for (int dt = 0; dt < 2; dt++)
        #pragma unroll
        for (int ks = 0; ks < 2; ks++)
            vf[dt][ks] = *(const half8*)&Vt[cb + dt * 16 + l16][ks * 32 + quad * 8];

    floatx4 O[2][2];
    #pragma unroll
    for (int mt = 0; mt < 2; mt++)
        #pragma unroll
        for (int dt = 0; dt < 2; dt++) {
            O[mt][dt] = (floatx4)0.f;
            #pragma unroll
            for (int ks = 0; ks < 2; ks++)
                O[mt][dt] = __builtin_amdgcn_mfma_f32_16x16x32_f16(
                    pf[mt][ks], vf[dt][ks], O[mt][dt], 0, 0, 0);
        }

    // Store: O row n = mt*16+quad*4+r, col e = cb+dt*16+l16; scale by 1/l
    const size_t obase = ((size_t)b * 4096 + n0) * 256;
    #pragma unroll
    for (int mt = 0; mt < 2; mt++)
        #pragma unroll
        for (int dt = 0; dt < 2; dt++)
            #pragma unroll
            for (int r = 0; r < 4; r++) {
                int n = mt * 16 + quad * 4 + r;
                out[obase + (size_t)n * 256 + cb + dt * 16 + l16] =
                    O[mt][dt][r] * inv[mt][r];
            }
}

extern "C" void kernel_launch(void* const* d_in, const int* in_sizes, int n_in,
                              void* d_out, int out_size, void* d_ws, size_t ws_size,
                              hipStream_t stream) {
    (void)in_sizes; (void)n_in; (void)out_size; (void)d_ws; (void)ws_size;
    const float* q    = (const float*)d_in[0];
    const float* k    = (const float*)d_in[1];
    const float* v    = (const float*)d_in[2];
    const float* W    = (const float*)d_in[3];
    const float* bias = (const float*)d_in[4];
    float* outp = (float*)d_out;

    hipLaunchKernelGGL(fused_kernel, dim3(128, 2), dim3(512), 0, stream,
                       q, k, v, W, bias, outp);
}